// Round 13
// baseline (447.156 us; speedup 1.0000x reference)
//
#include <hip/hip_runtime.h>
#include <cstdint>
#include <cstddef>

#define NNODES 100000
#define NGRAPHS 128
#define NEG_SLOPE 0.2f
#define MAXDEG 64    // real edges only (self handled in aggregate); deg ~ Poisson(16)

typedef __attribute__((ext_vector_type(8))) short short8;
typedef __attribute__((ext_vector_type(4))) float f32x4;

static __device__ __forceinline__ unsigned int bf16_rne(float f) {
    unsigned int x = __float_as_uint(f);
    return (x + 0x7fffu + ((x >> 16) & 1u)) >> 16;
}

// ---------- W pre-transpose/convert (both layers in one launch) ----------
__global__ void prep_w_kernel(const float* __restrict__ W1, const float* __restrict__ W2,
                              unsigned short* __restrict__ wt1, unsigned short* __restrict__ wt2) {
    int idx = blockIdx.x * 256 + threadIdx.x;
    if (idx < 128 * 128) {
        int c = idx & 127, k = idx >> 7;
        wt1[c * 128 + k] = (unsigned short)bf16_rne(W1[k * 128 + c]);
    } else {
        int j = idx - 128 * 128;
        if (j < 128 * 64) {
            int c = j & 127, k = j >> 7;
            wt2[c * 64 + k] = (unsigned short)bf16_rne(W2[k * 128 + c]);
        }
    }
}

// ---------- LDS-free MFMA GEMM body + pack + attention epilogue ----------
// C = A[M,K] @ W[K,128]; one block = 64 rows x 128 cols; B fragments read
// directly from the pre-converted, transposed Wt (32KB, L1/L2-resident).
template <int K, bool BF16IN>
static __device__ __forceinline__ void gemm_body(
        int bx, int tid, const void* __restrict__ Av, const unsigned short* __restrict__ Wt,
        unsigned short* __restrict__ xwp16,
        const float* __restrict__ att_src, const float* __restrict__ att_dst,
        float* __restrict__ asrc, float* __restrict__ adst, int M) {
    int row0 = bx * 64;
    int w = tid >> 6, l = tid & 63;
    int lr = l & 15, lg = l >> 4;
    int row = row0 + 16 * w + lr;
    bool rv = row < M;

    short8 afr[K / 32];
    if constexpr (BF16IN) {
        const unsigned short* A = (const unsigned short*)Av;
        #pragma unroll
        for (int ks = 0; ks < K / 32; ++ks) {
            short8 v = {};
            if (rv) v = *(const short8*)&A[(size_t)row * K + lg * 8 + ks * 32];
            afr[ks] = v;
        }
    } else {
        const float* A = (const float*)Av;
        #pragma unroll
        for (int ks = 0; ks < K / 32; ++ks) {
            short8 v = {};
            if (rv) {
                float4 f0 = *(const float4*)&A[(size_t)row * K + lg * 8 + ks * 32];
                float4 f1 = *(const float4*)&A[(size_t)row * K + lg * 8 + ks * 32 + 4];
                v[0] = (short)bf16_rne(f0.x); v[1] = (short)bf16_rne(f0.y);
                v[2] = (short)bf16_rne(f0.z); v[3] = (short)bf16_rne(f0.w);
                v[4] = (short)bf16_rne(f1.x); v[5] = (short)bf16_rne(f1.y);
                v[6] = (short)bf16_rne(f1.z); v[7] = (short)bf16_rne(f1.w);
            }
            afr[ks] = v;
        }
    }

    f32x4 acc[8] = {};
    #pragma unroll
    for (int ks = 0; ks < K / 32; ++ks) {
        #pragma unroll
        for (int t = 0; t < 8; ++t) {
            short8 b = *(const short8*)&Wt[(size_t)(16 * t + lr) * K + lg * 8 + ks * 32];
            acc[t] = __builtin_amdgcn_mfma_f32_16x16x32_bf16(afr[ks], b, acc[t], 0, 0, 0);
        }
    }

    float ps0[4] = {}, pd0[4] = {}, ps1[4] = {}, pd1[4] = {};
    #pragma unroll
    for (int t = 0; t < 8; ++t) {
        int c = 16 * t + lr;
        int h = t >> 2;
        int cc = c & 63;
        float ws = att_src[h * 64 + cc];
        float wd = att_dst[h * 64 + cc];
        #pragma unroll
        for (int r = 0; r < 4; ++r) {
            int orow = row0 + 16 * w + lg * 4 + r;
            float v = acc[t][r];
            if (h == 0) { ps0[r] += v * ws; pd0[r] += v * wd; }
            else        { ps1[r] += v * ws; pd1[r] += v * wd; }
            if (orow < M) xwp16[(size_t)orow * 128 + cc * 2 + h] = (unsigned short)bf16_rne(v);
        }
    }
    #pragma unroll
    for (int off = 1; off < 16; off <<= 1) {
        #pragma unroll
        for (int r = 0; r < 4; ++r) {
            ps0[r] += __shfl_xor(ps0[r], off);
            pd0[r] += __shfl_xor(pd0[r], off);
            ps1[r] += __shfl_xor(ps1[r], off);
            pd1[r] += __shfl_xor(pd1[r], off);
        }
    }
    if (lr == 0) {
        #pragma unroll
        for (int r = 0; r < 4; ++r) {
            int orow = row0 + 16 * w + lg * 4 + r;
            if (orow < M) {
                asrc[orow * 2 + 0] = ps0[r]; adst[orow * 2 + 0] = pd0[r];
                asrc[orow * 2 + 1] = ps1[r]; adst[orow * 2 + 1] = pd1[r];
            }
        }
    }
}

// ---------- fused: CSR scatter (VMEM-bound) || layer-1 GEMM (MFMA-bound) ----------
__global__ __launch_bounds__(256) void fused_scatter_gemm1_kernel(
        const int* __restrict__ src, const int* __restrict__ dst,
        int* __restrict__ cursor, int* __restrict__ esrc, int E, int nscat,
        const float* __restrict__ A, const unsigned short* __restrict__ Wt,
        unsigned short* __restrict__ xwp16,
        const float* __restrict__ att_src, const float* __restrict__ att_dst,
        float* __restrict__ asrc, float* __restrict__ adst, int M) {
    if ((int)blockIdx.x < nscat) {
        int e = blockIdx.x * 256 + threadIdx.x;
        if (e < E) {
            int s = src[e], d = dst[e];
            int slot = atomicAdd(&cursor[d], 1);
            __builtin_nontemporal_store(s, &esrc[(size_t)d * MAXDEG + slot]);
        }
        return;
    }
    gemm_body<128, false>(blockIdx.x - nscat, threadIdx.x, A, Wt, xwp16,
                          att_src, att_dst, asrc, adst, M);
}

// ---------- standalone layer-2 GEMM ----------
__global__ __launch_bounds__(256) void gemm2_kernel(
        const unsigned short* __restrict__ A, const unsigned short* __restrict__ Wt,
        unsigned short* __restrict__ xwp16,
        const float* __restrict__ att_src, const float* __restrict__ att_dst,
        float* __restrict__ asrc, float* __restrict__ adst, int M) {
    gemm_body<64, true>(blockIdx.x, threadIdx.x, A, Wt, xwp16,
                        att_src, att_dst, asrc, adst, M);
}

// ---------- fused softmax + gather-aggregate: one 64-thread block per node ----------
// Self-loop handled directly (seeds the accumulator); esrc holds real edges only.
template <bool TO_G>
__global__ __launch_bounds__(64) void aggregate_kernel(
        const int* __restrict__ deg, const int* __restrict__ esrc,
        const float2* __restrict__ asrc2, const float2* __restrict__ adst2,
        const unsigned int* __restrict__ xwp, const float* __restrict__ bias,
        unsigned short* __restrict__ outb, const int* __restrict__ batch,
        float* __restrict__ g) {
    int lane = threadIdx.x;
    int n = blockIdx.x;
    int row = n * MAXDEG, dg = deg[n];
    float2 ad = adst2[n];
    float acc0, acc1, s0, s1;
    // self contribution
    {
        float2 a = asrc2[n];
        unsigned int u = xwp[(size_t)n * 64 + lane];
        float l0 = a.x + ad.x, l1 = a.y + ad.y;
        l0 = fmaxf(l0, NEG_SLOPE * l0); l1 = fmaxf(l1, NEG_SLOPE * l1);
        float e0 = __expf(l0), e1 = __expf(l1);
        s0 = e0; s1 = e1;
        acc0 = e0 * __uint_as_float(u << 16);
        acc1 = e1 * __uint_as_float(u & 0xffff0000u);
    }
    int i = 0;

#define LOADG(k) int sn##k = __builtin_nontemporal_load(&esrc[row + i + k]); \
                 float2 a##k = asrc2[sn##k]; \
                 unsigned int u##k = xwp[(size_t)sn##k * 64 + lane]
#define FMAG(k)  { float l0 = a##k.x + ad.x; float l1 = a##k.y + ad.y; \
                   l0 = fmaxf(l0, NEG_SLOPE * l0); l1 = fmaxf(l1, NEG_SLOPE * l1); \
                   float e0 = __expf(l0), e1 = __expf(l1); \
                   s0 += e0; s1 += e1; \
                   acc0 += e0 * __uint_as_float(u##k << 16); \
                   acc1 += e1 * __uint_as_float(u##k & 0xffff0000u); }

    for (; i + 8 <= dg; i += 8) {
        LOADG(0); LOADG(1); LOADG(2); LOADG(3);
        LOADG(4); LOADG(5); LOADG(6); LOADG(7);
        FMAG(0); FMAG(1); FMAG(2); FMAG(3);
        FMAG(4); FMAG(5); FMAG(6); FMAG(7);
    }
    for (; i + 2 <= dg; i += 2) {
        LOADG(0); LOADG(1);
        FMAG(0); FMAG(1);
    }
    if (i < dg) {
        LOADG(0);
        FMAG(0);
    }
#undef LOADG
#undef FMAG

    float v = 0.5f * (acc0 / (s0 + 1e-16f) + acc1 / (s1 + 1e-16f)) + bias[lane];
    v = (v > 0.f) ? v : 0.f;
    if (TO_G) atomicAdd(&g[batch[n] * 64 + lane], v);
    else outb[(size_t)n * 64 + lane] = (unsigned short)bf16_rne(v);
}

// ---------- final FC + log_softmax ----------
__global__ void final_fc_kernel(const float* __restrict__ g, const float* __restrict__ Wfc,
                                const float* __restrict__ bfc, float* __restrict__ out) {
    int gi = threadIdx.x;
    if (gi >= NGRAPHS) return;
    float logit[10];
    #pragma unroll
    for (int o = 0; o < 10; ++o) logit[o] = bfc[o];
    for (int c = 0; c < 64; ++c) {
        float gv = g[gi * 64 + c];
        #pragma unroll
        for (int o = 0; o < 10; ++o) logit[o] += gv * Wfc[c * 10 + o];
    }
    float mx = logit[0];
    #pragma unroll
    for (int o = 1; o < 10; ++o) mx = fmaxf(mx, logit[o]);
    float se = 0.f;
    #pragma unroll
    for (int o = 0; o < 10; ++o) se += expf(logit[o] - mx);
    float lse = mx + logf(se);
    #pragma unroll
    for (int o = 0; o < 10; ++o) out[gi * 10 + o] = logit[o] - lse;
}

extern "C" void kernel_launch(void* const* d_in, const int* in_sizes, int n_in,
                              void* d_out, int out_size, void* d_ws, size_t ws_size,
                              hipStream_t stream) {
    const float* x        = (const float*)d_in[0];
    const float* W1       = (const float*)d_in[1];
    const float* att_src1 = (const float*)d_in[2];
    const float* att_dst1 = (const float*)d_in[3];
    const float* b1       = (const float*)d_in[4];
    const float* W2       = (const float*)d_in[5];
    const float* att_src2 = (const float*)d_in[6];
    const float* att_dst2 = (const float*)d_in[7];
    const float* b2       = (const float*)d_in[8];
    const float* Wfc      = (const float*)d_in[9];
    const float* bfc      = (const float*)d_in[10];
    const int*   eidx     = (const int*)d_in[11];
    const int*   batch    = (const int*)d_in[12];
    float* out = (float*)d_out;

    const int E  = in_sizes[11] / 2;
    const int* srcp = eidx;
    const int* dstp = eidx + E;

    // workspace layout (cursor and g contiguous -> single memset)
    char* w = (char*)d_ws;
    unsigned int* xwp = (unsigned int*)w;    w += (size_t)NNODES * 64 * 4;
    float* asrc = (float*)w;                 w += (size_t)NNODES * 2 * 4;
    float* adst = (float*)w;                 w += (size_t)NNODES * 2 * 4;
    unsigned short* h1 = (unsigned short*)w; w += (size_t)NNODES * 64 * 2;
    int* cursor  = (int*)w;                  w += (size_t)NNODES * 4;
    float* g    = (float*)w;                 w += (size_t)NGRAPHS * 64 * 4;
    int* esrc    = (int*)w;                  w += (size_t)NNODES * MAXDEG * 4;
    unsigned short* wt1 = (unsigned short*)w; w += (size_t)128 * 128 * 2;
    unsigned short* wt2 = (unsigned short*)w; w += (size_t)128 * 64 * 2;

    const int BLK = 256;
    int nscat = (E + BLK - 1) / BLK;
    int gemm_grid = (NNODES + 63) / 64;

    // ---- single memset for cursor + g ----
    hipMemsetAsync(cursor, 0, ((size_t)NNODES + NGRAPHS * 64) * 4, stream);

    // ---- W pre-conversion ----
    prep_w_kernel<<<(128 * 192 + 255) / 256, 256, 0, stream>>>(W1, W2, wt1, wt2);

    // ---- fused: CSR scatter || layer-1 GEMM ----
    fused_scatter_gemm1_kernel<<<nscat + gemm_grid, BLK, 0, stream>>>(
        srcp, dstp, cursor, esrc, E, nscat,
        x, wt1, (unsigned short*)xwp, att_src1, att_dst1, asrc, adst, NNODES);

    // ---- layer 1 aggregate ----
    aggregate_kernel<false><<<NNODES, 64, 0, stream>>>(cursor, esrc,
                                                       (const float2*)asrc, (const float2*)adst,
                                                       xwp, b1, h1, nullptr, nullptr);

    // ---- layer 2 ----
    gemm2_kernel<<<gemm_grid, BLK, 0, stream>>>(h1, wt2, (unsigned short*)xwp,
                                                att_src2, att_dst2, asrc, adst, NNODES);
    aggregate_kernel<true><<<NNODES, 64, 0, stream>>>(cursor, esrc,
                                                      (const float2*)asrc, (const float2*)adst,
                                                      xwp, b2, nullptr, batch, g);

    // ---- final FC + log_softmax ----
    final_fc_kernel<<<1, 128, 0, stream>>>(g, Wfc, bfc, out);
}

// Round 14
// 387.311 us; speedup vs baseline: 1.1545x; 1.1545x over previous
//
#include <hip/hip_runtime.h>
#include <cstdint>
#include <cstddef>

#define NNODES 100000
#define NGRAPHS 128
#define NEG_SLOPE 0.2f
#define MAXDEG 64    // real edges only (self handled in aggregate); deg ~ Poisson(16)

typedef __attribute__((ext_vector_type(8))) short short8;
typedef __attribute__((ext_vector_type(4))) float f32x4;

static __device__ __forceinline__ unsigned int bf16_rne(float f) {
    unsigned int x = __float_as_uint(f);
    return (x + 0x7fffu + ((x >> 16) & 1u)) >> 16;
}

// ---------- W pre-transpose/convert (both layers in one launch) ----------
__global__ void prep_w_kernel(const float* __restrict__ W1, const float* __restrict__ W2,
                              unsigned short* __restrict__ wt1, unsigned short* __restrict__ wt2) {
    int idx = blockIdx.x * 256 + threadIdx.x;
    if (idx < 128 * 128) {
        int c = idx & 127, k = idx >> 7;
        wt1[c * 128 + k] = (unsigned short)bf16_rne(W1[k * 128 + c]);
    } else {
        int j = idx - 128 * 128;
        if (j < 128 * 64) {
            int c = j & 127, k = j >> 7;
            wt2[c * 64 + k] = (unsigned short)bf16_rne(W2[k * 128 + c]);
        }
    }
}

// ---------- fused MFMA GEMM (LDS-staged B) + bf16 pack + attention coefficients ----------
template <int K, bool BF16IN>
__global__ __launch_bounds__(256) void gemm_mfma_kernel(
        const void* __restrict__ Av, const unsigned short* __restrict__ Wt,
        unsigned short* __restrict__ xwp16,
        const float* __restrict__ att_src, const float* __restrict__ att_dst,
        float* __restrict__ asrc, float* __restrict__ adst, int M) {
    constexpr int BST = K + 8;
    __shared__ __align__(16) unsigned short B_lds[128 * BST];
    int tid = threadIdx.x;
    int row0 = blockIdx.x * 64;

    constexpr int K8 = K / 8;
    #pragma unroll
    for (int i = 0; i < 128 * K8 / 256; ++i) {
        int idx = tid + i * 256;
        int c = idx / K8, k8 = idx % K8;
        *(short8*)&B_lds[c * BST + k8 * 8] = *(const short8*)&Wt[c * K + k8 * 8];
    }
    __syncthreads();

    int w = tid >> 6, l = tid & 63;
    int lr = l & 15, lg = l >> 4;
    int row = row0 + 16 * w + lr;
    bool rv = row < M;

    short8 afr[K / 32];
    if constexpr (BF16IN) {
        const unsigned short* A = (const unsigned short*)Av;
        #pragma unroll
        for (int ks = 0; ks < K / 32; ++ks) {
            short8 v = {};
            if (rv) v = *(const short8*)&A[(size_t)row * K + lg * 8 + ks * 32];
            afr[ks] = v;
        }
    } else {
        const float* A = (const float*)Av;
        #pragma unroll
        for (int ks = 0; ks < K / 32; ++ks) {
            short8 v = {};
            if (rv) {
                float4 f0 = *(const float4*)&A[(size_t)row * K + lg * 8 + ks * 32];
                float4 f1 = *(const float4*)&A[(size_t)row * K + lg * 8 + ks * 32 + 4];
                v[0] = (short)bf16_rne(f0.x); v[1] = (short)bf16_rne(f0.y);
                v[2] = (short)bf16_rne(f0.z); v[3] = (short)bf16_rne(f0.w);
                v[4] = (short)bf16_rne(f1.x); v[5] = (short)bf16_rne(f1.y);
                v[6] = (short)bf16_rne(f1.z); v[7] = (short)bf16_rne(f1.w);
            }
            afr[ks] = v;
        }
    }

    f32x4 acc[8] = {};
    #pragma unroll
    for (int ks = 0; ks < K / 32; ++ks) {
        #pragma unroll
        for (int t = 0; t < 8; ++t) {
            short8 b = *(const short8*)&B_lds[(16 * t + lr) * BST + lg * 8 + ks * 32];
            acc[t] = __builtin_amdgcn_mfma_f32_16x16x32_bf16(afr[ks], b, acc[t], 0, 0, 0);
        }
    }

    float ps0[4] = {}, pd0[4] = {}, ps1[4] = {}, pd1[4] = {};
    #pragma unroll
    for (int t = 0; t < 8; ++t) {
        int c = 16 * t + lr;
        int h = t >> 2;
        int cc = c & 63;
        float ws = att_src[h * 64 + cc];
        float wd = att_dst[h * 64 + cc];
        #pragma unroll
        for (int r = 0; r < 4; ++r) {
            int orow = row0 + 16 * w + lg * 4 + r;
            float v = acc[t][r];
            if (h == 0) { ps0[r] += v * ws; pd0[r] += v * wd; }
            else        { ps1[r] += v * ws; pd1[r] += v * wd; }
            if (orow < M) xwp16[(size_t)orow * 128 + cc * 2 + h] = (unsigned short)bf16_rne(v);
        }
    }
    #pragma unroll
    for (int off = 1; off < 16; off <<= 1) {
        #pragma unroll
        for (int r = 0; r < 4; ++r) {
            ps0[r] += __shfl_xor(ps0[r], off);
            pd0[r] += __shfl_xor(pd0[r], off);
            ps1[r] += __shfl_xor(ps1[r], off);
            pd1[r] += __shfl_xor(pd1[r], off);
        }
    }
    if (lr == 0) {
        #pragma unroll
        for (int r = 0; r < 4; ++r) {
            int orow = row0 + 16 * w + lg * 4 + r;
            if (orow < M) {
                asrc[orow * 2 + 0] = ps0[r]; adst[orow * 2 + 0] = pd0[r];
                asrc[orow * 2 + 1] = ps1[r]; adst[orow * 2 + 1] = pd1[r];
            }
        }
    }
}

// ---------- fixed-slot CSR scatter (real edges only; NT store) ----------
__global__ void scatter_kernel(const int* __restrict__ src, const int* __restrict__ dst,
                               int* __restrict__ cursor, int* __restrict__ esrc, int E) {
    int e = blockIdx.x * blockDim.x + threadIdx.x;
    if (e >= E) return;
    int s = src[e], d = dst[e];
    int slot = atomicAdd(&cursor[d], 1);
    __builtin_nontemporal_store(s, &esrc[(size_t)d * MAXDEG + slot]);
}

// ---------- fused softmax + gather-aggregate: one 64-thread block per node ----------
// Self-loop seeds the accumulator; esrc holds real edges only.
template <bool TO_G>
__global__ __launch_bounds__(64) void aggregate_kernel(
        const int* __restrict__ deg, const int* __restrict__ esrc,
        const float2* __restrict__ asrc2, const float2* __restrict__ adst2,
        const unsigned int* __restrict__ xwp, const float* __restrict__ bias,
        unsigned short* __restrict__ outb, const int* __restrict__ batch,
        float* __restrict__ g) {
    int lane = threadIdx.x;
    int n = blockIdx.x;
    int row = n * MAXDEG, dg = deg[n];
    float2 ad = adst2[n];
    float acc0, acc1, s0, s1;
    {
        float2 a = asrc2[n];
        unsigned int u = xwp[(size_t)n * 64 + lane];
        float l0 = a.x + ad.x, l1 = a.y + ad.y;
        l0 = fmaxf(l0, NEG_SLOPE * l0); l1 = fmaxf(l1, NEG_SLOPE * l1);
        float e0 = __expf(l0), e1 = __expf(l1);
        s0 = e0; s1 = e1;
        acc0 = e0 * __uint_as_float(u << 16);
        acc1 = e1 * __uint_as_float(u & 0xffff0000u);
    }
    int i = 0;

#define LOADG(k) int sn##k = __builtin_nontemporal_load(&esrc[row + i + k]); \
                 float2 a##k = asrc2[sn##k]; \
                 unsigned int u##k = xwp[(size_t)sn##k * 64 + lane]
#define FMAG(k)  { float l0 = a##k.x + ad.x; float l1 = a##k.y + ad.y; \
                   l0 = fmaxf(l0, NEG_SLOPE * l0); l1 = fmaxf(l1, NEG_SLOPE * l1); \
                   float e0 = __expf(l0), e1 = __expf(l1); \
                   s0 += e0; s1 += e1; \
                   acc0 += e0 * __uint_as_float(u##k << 16); \
                   acc1 += e1 * __uint_as_float(u##k & 0xffff0000u); }

    for (; i + 8 <= dg; i += 8) {
        LOADG(0); LOADG(1); LOADG(2); LOADG(3);
        LOADG(4); LOADG(5); LOADG(6); LOADG(7);
        FMAG(0); FMAG(1); FMAG(2); FMAG(3);
        FMAG(4); FMAG(5); FMAG(6); FMAG(7);
    }
    for (; i + 2 <= dg; i += 2) {
        LOADG(0); LOADG(1);
        FMAG(0); FMAG(1);
    }
    if (i < dg) {
        LOADG(0);
        FMAG(0);
    }
#undef LOADG
#undef FMAG

    float v = 0.5f * (acc0 / (s0 + 1e-16f) + acc1 / (s1 + 1e-16f)) + bias[lane];
    v = (v > 0.f) ? v : 0.f;
    if (TO_G) atomicAdd(&g[batch[n] * 64 + lane], v);
    else outb[(size_t)n * 64 + lane] = (unsigned short)bf16_rne(v);
}

// ---------- final FC + log_softmax ----------
__global__ void final_fc_kernel(const float* __restrict__ g, const float* __restrict__ Wfc,
                                const float* __restrict__ bfc, float* __restrict__ out) {
    int gi = threadIdx.x;
    if (gi >= NGRAPHS) return;
    float logit[10];
    #pragma unroll
    for (int o = 0; o < 10; ++o) logit[o] = bfc[o];
    for (int c = 0; c < 64; ++c) {
        float gv = g[gi * 64 + c];
        #pragma unroll
        for (int o = 0; o < 10; ++o) logit[o] += gv * Wfc[c * 10 + o];
    }
    float mx = logit[0];
    #pragma unroll
    for (int o = 1; o < 10; ++o) mx = fmaxf(mx, logit[o]);
    float se = 0.f;
    #pragma unroll
    for (int o = 0; o < 10; ++o) se += expf(logit[o] - mx);
    float lse = mx + logf(se);
    #pragma unroll
    for (int o = 0; o < 10; ++o) out[gi * 10 + o] = logit[o] - lse;
}

extern "C" void kernel_launch(void* const* d_in, const int* in_sizes, int n_in,
                              void* d_out, int out_size, void* d_ws, size_t ws_size,
                              hipStream_t stream) {
    const float* x        = (const float*)d_in[0];
    const float* W1       = (const float*)d_in[1];
    const float* att_src1 = (const float*)d_in[2];
    const float* att_dst1 = (const float*)d_in[3];
    const float* b1       = (const float*)d_in[4];
    const float* W2       = (const float*)d_in[5];
    const float* att_src2 = (const float*)d_in[6];
    const float* att_dst2 = (const float*)d_in[7];
    const float* b2       = (const float*)d_in[8];
    const float* Wfc      = (const float*)d_in[9];
    const float* bfc      = (const float*)d_in[10];
    const int*   eidx     = (const int*)d_in[11];
    const int*   batch    = (const int*)d_in[12];
    float* out = (float*)d_out;

    const int E  = in_sizes[11] / 2;
    const int* srcp = eidx;
    const int* dstp = eidx + E;

    // workspace layout (cursor and g contiguous -> single memset)
    char* w = (char*)d_ws;
    unsigned int* xwp = (unsigned int*)w;    w += (size_t)NNODES * 64 * 4;
    float* asrc = (float*)w;                 w += (size_t)NNODES * 2 * 4;
    float* adst = (float*)w;                 w += (size_t)NNODES * 2 * 4;
    unsigned short* h1 = (unsigned short*)w; w += (size_t)NNODES * 64 * 2;
    int* cursor  = (int*)w;                  w += (size_t)NNODES * 4;
    float* g    = (float*)w;                 w += (size_t)NGRAPHS * 64 * 4;
    int* esrc    = (int*)w;                  w += (size_t)NNODES * MAXDEG * 4;
    unsigned short* wt1 = (unsigned short*)w; w += (size_t)128 * 128 * 2;
    unsigned short* wt2 = (unsigned short*)w; w += (size_t)128 * 64 * 2;

    const int BLK = 256;
    int grid_e    = (E + BLK - 1) / BLK;
    int gemm_grid = (NNODES + 63) / 64;

    // ---- single memset for cursor + g ----
    hipMemsetAsync(cursor, 0, ((size_t)NNODES + NGRAPHS * 64) * 4, stream);

    // ---- CSR scatter (real edges only; cursor becomes deg) + W pre-conversion ----
    scatter_kernel<<<grid_e, BLK, 0, stream>>>(srcp, dstp, cursor, esrc, E);
    prep_w_kernel<<<(128 * 192 + 255) / 256, 256, 0, stream>>>(W1, W2, wt1, wt2);

    // ---- layer 1 ----
    gemm_mfma_kernel<128, false><<<gemm_grid, BLK, 0, stream>>>(x, wt1, (unsigned short*)xwp,
                                                                att_src1, att_dst1, asrc, adst, NNODES);
    aggregate_kernel<false><<<NNODES, 64, 0, stream>>>(cursor, esrc,
                                                       (const float2*)asrc, (const float2*)adst,
                                                       xwp, b1, h1, nullptr, nullptr);

    // ---- layer 2 ----
    gemm_mfma_kernel<64, true><<<gemm_grid, BLK, 0, stream>>>(h1, wt2, (unsigned short*)xwp,
                                                              att_src2, att_dst2, asrc, adst, NNODES);
    aggregate_kernel<true><<<NNODES, 64, 0, stream>>>(cursor, esrc,
                                                      (const float2*)asrc, (const float2*)adst,
                                                      xwp, b2, nullptr, batch, g);

    // ---- final FC + log_softmax ----
    final_fc_kernel<<<1, 128, 0, stream>>>(g, Wfc, bfc, out);
}

// Round 15
// 362.486 us; speedup vs baseline: 1.2336x; 1.0685x over previous
//
#include <hip/hip_runtime.h>
#include <cstdint>
#include <cstddef>

#define NNODES 100000
#define NGRAPHS 128
#define NEG_SLOPE 0.2f
#define MAXDEG 64    // real edges only (self handled in aggregate); deg ~ Poisson(16)

typedef __attribute__((ext_vector_type(8))) short short8;
typedef __attribute__((ext_vector_type(4))) float f32x4;

static __device__ __forceinline__ unsigned int bf16_rne(float f) {
    unsigned int x = __float_as_uint(f);
    return (x + 0x7fffu + ((x >> 16) & 1u)) >> 16;
}

// ---------- W pre-transpose/convert (both layers in one launch) ----------
__global__ void prep_w_kernel(const float* __restrict__ W1, const float* __restrict__ W2,
                              unsigned short* __restrict__ wt1, unsigned short* __restrict__ wt2) {
    int idx = blockIdx.x * 256 + threadIdx.x;
    if (idx < 128 * 128) {
        int c = idx & 127, k = idx >> 7;
        wt1[c * 128 + k] = (unsigned short)bf16_rne(W1[k * 128 + c]);
    } else {
        int j = idx - 128 * 128;
        if (j < 128 * 64) {
            int c = j & 127, k = j >> 7;
            wt2[c * 64 + k] = (unsigned short)bf16_rne(W2[k * 128 + c]);
        }
    }
}

// ---------- fused MFMA GEMM (LDS-staged B) + bf16 pack + attention coefficients ----------
template <int K, bool BF16IN>
__global__ __launch_bounds__(256) void gemm_mfma_kernel(
        const void* __restrict__ Av, const unsigned short* __restrict__ Wt,
        unsigned short* __restrict__ xwp16,
        const float* __restrict__ att_src, const float* __restrict__ att_dst,
        float* __restrict__ asrc, float* __restrict__ adst, int M) {
    constexpr int BST = K + 8;
    __shared__ __align__(16) unsigned short B_lds[128 * BST];
    int tid = threadIdx.x;
    int row0 = blockIdx.x * 64;

    constexpr int K8 = K / 8;
    #pragma unroll
    for (int i = 0; i < 128 * K8 / 256; ++i) {
        int idx = tid + i * 256;
        int c = idx / K8, k8 = idx % K8;
        *(short8*)&B_lds[c * BST + k8 * 8] = *(const short8*)&Wt[c * K + k8 * 8];
    }
    __syncthreads();

    int w = tid >> 6, l = tid & 63;
    int lr = l & 15, lg = l >> 4;
    int row = row0 + 16 * w + lr;
    bool rv = row < M;

    short8 afr[K / 32];
    if constexpr (BF16IN) {
        const unsigned short* A = (const unsigned short*)Av;
        #pragma unroll
        for (int ks = 0; ks < K / 32; ++ks) {
            short8 v = {};
            if (rv) v = *(const short8*)&A[(size_t)row * K + lg * 8 + ks * 32];
            afr[ks] = v;
        }
    } else {
        const float* A = (const float*)Av;
        #pragma unroll
        for (int ks = 0; ks < K / 32; ++ks) {
            short8 v = {};
            if (rv) {
                float4 f0 = *(const float4*)&A[(size_t)row * K + lg * 8 + ks * 32];
                float4 f1 = *(const float4*)&A[(size_t)row * K + lg * 8 + ks * 32 + 4];
                v[0] = (short)bf16_rne(f0.x); v[1] = (short)bf16_rne(f0.y);
                v[2] = (short)bf16_rne(f0.z); v[3] = (short)bf16_rne(f0.w);
                v[4] = (short)bf16_rne(f1.x); v[5] = (short)bf16_rne(f1.y);
                v[6] = (short)bf16_rne(f1.z); v[7] = (short)bf16_rne(f1.w);
            }
            afr[ks] = v;
        }
    }

    f32x4 acc[8] = {};
    #pragma unroll
    for (int ks = 0; ks < K / 32; ++ks) {
        #pragma unroll
        for (int t = 0; t < 8; ++t) {
            short8 b = *(const short8*)&B_lds[(16 * t + lr) * BST + lg * 8 + ks * 32];
            acc[t] = __builtin_amdgcn_mfma_f32_16x16x32_bf16(afr[ks], b, acc[t], 0, 0, 0);
        }
    }

    float ps0[4] = {}, pd0[4] = {}, ps1[4] = {}, pd1[4] = {};
    #pragma unroll
    for (int t = 0; t < 8; ++t) {
        int c = 16 * t + lr;
        int h = t >> 2;
        int cc = c & 63;
        float ws = att_src[h * 64 + cc];
        float wd = att_dst[h * 64 + cc];
        #pragma unroll
        for (int r = 0; r < 4; ++r) {
            int orow = row0 + 16 * w + lg * 4 + r;
            float v = acc[t][r];
            if (h == 0) { ps0[r] += v * ws; pd0[r] += v * wd; }
            else        { ps1[r] += v * ws; pd1[r] += v * wd; }
            if (orow < M) xwp16[(size_t)orow * 128 + cc * 2 + h] = (unsigned short)bf16_rne(v);
        }
    }
    #pragma unroll
    for (int off = 1; off < 16; off <<= 1) {
        #pragma unroll
        for (int r = 0; r < 4; ++r) {
            ps0[r] += __shfl_xor(ps0[r], off);
            pd0[r] += __shfl_xor(pd0[r], off);
            ps1[r] += __shfl_xor(ps1[r], off);
            pd1[r] += __shfl_xor(pd1[r], off);
        }
    }
    if (lr == 0) {
        #pragma unroll
        for (int r = 0; r < 4; ++r) {
            int orow = row0 + 16 * w + lg * 4 + r;
            if (orow < M) {
                asrc[orow * 2 + 0] = ps0[r]; adst[orow * 2 + 0] = pd0[r];
                asrc[orow * 2 + 1] = ps1[r]; adst[orow * 2 + 1] = pd1[r];
            }
        }
    }
}

// ---------- fixed-slot CSR scatter: 2 edges per thread (2 independent chains) ----------
__global__ void scatter_kernel(const int* __restrict__ src, const int* __restrict__ dst,
                               int* __restrict__ cursor, int* __restrict__ esrc, int E) {
    int t = blockIdx.x * blockDim.x + threadIdx.x;
    int e0 = t * 2;
    if (e0 >= E) return;
    if (e0 + 1 < E) {
        int2 s = *(const int2*)&src[e0];
        int2 d = *(const int2*)&dst[e0];
        int slot0 = atomicAdd(&cursor[d.x], 1);
        int slot1 = atomicAdd(&cursor[d.y], 1);
        esrc[(size_t)d.x * MAXDEG + slot0] = s.x;
        esrc[(size_t)d.y * MAXDEG + slot1] = s.y;
    } else {
        int s = src[e0], d = dst[e0];
        int slot = atomicAdd(&cursor[d], 1);
        esrc[(size_t)d * MAXDEG + slot] = s;
    }
}

// ---------- fused softmax + gather-aggregate: one 64-thread block per node ----------
// Self-loop seeds the accumulator; esrc holds real edges only.
template <bool TO_G>
__global__ __launch_bounds__(64) void aggregate_kernel(
        const int* __restrict__ deg, const int* __restrict__ esrc,
        const float2* __restrict__ asrc2, const float2* __restrict__ adst2,
        const unsigned int* __restrict__ xwp, const float* __restrict__ bias,
        unsigned short* __restrict__ outb, const int* __restrict__ batch,
        float* __restrict__ g) {
    int lane = threadIdx.x;
    int n = blockIdx.x;
    int row = n * MAXDEG, dg = deg[n];
    float2 ad = adst2[n];
    float acc0, acc1, s0, s1;
    {
        float2 a = asrc2[n];
        unsigned int u = xwp[(size_t)n * 64 + lane];
        float l0 = a.x + ad.x, l1 = a.y + ad.y;
        l0 = fmaxf(l0, NEG_SLOPE * l0); l1 = fmaxf(l1, NEG_SLOPE * l1);
        float e0 = __expf(l0), e1 = __expf(l1);
        s0 = e0; s1 = e1;
        acc0 = e0 * __uint_as_float(u << 16);
        acc1 = e1 * __uint_as_float(u & 0xffff0000u);
    }
    int i = 0;

#define LOADG(k) int sn##k = __builtin_nontemporal_load(&esrc[row + i + k]); \
                 float2 a##k = asrc2[sn##k]; \
                 unsigned int u##k = xwp[(size_t)sn##k * 64 + lane]
#define FMAG(k)  { float l0 = a##k.x + ad.x; float l1 = a##k.y + ad.y; \
                   l0 = fmaxf(l0, NEG_SLOPE * l0); l1 = fmaxf(l1, NEG_SLOPE * l1); \
                   float e0 = __expf(l0), e1 = __expf(l1); \
                   s0 += e0; s1 += e1; \
                   acc0 += e0 * __uint_as_float(u##k << 16); \
                   acc1 += e1 * __uint_as_float(u##k & 0xffff0000u); }

    for (; i + 8 <= dg; i += 8) {
        LOADG(0); LOADG(1); LOADG(2); LOADG(3);
        LOADG(4); LOADG(5); LOADG(6); LOADG(7);
        FMAG(0); FMAG(1); FMAG(2); FMAG(3);
        FMAG(4); FMAG(5); FMAG(6); FMAG(7);
    }
    for (; i + 2 <= dg; i += 2) {
        LOADG(0); LOADG(1);
        FMAG(0); FMAG(1);
    }
    if (i < dg) {
        LOADG(0);
        FMAG(0);
    }
#undef LOADG
#undef FMAG

    float v = 0.5f * (acc0 / (s0 + 1e-16f) + acc1 / (s1 + 1e-16f)) + bias[lane];
    v = (v > 0.f) ? v : 0.f;
    if (TO_G) atomicAdd(&g[batch[n] * 64 + lane], v);
    else outb[(size_t)n * 64 + lane] = (unsigned short)bf16_rne(v);
}

// ---------- final FC + log_softmax ----------
__global__ void final_fc_kernel(const float* __restrict__ g, const float* __restrict__ Wfc,
                                const float* __restrict__ bfc, float* __restrict__ out) {
    int gi = threadIdx.x;
    if (gi >= NGRAPHS) return;
    float logit[10];
    #pragma unroll
    for (int o = 0; o < 10; ++o) logit[o] = bfc[o];
    for (int c = 0; c < 64; ++c) {
        float gv = g[gi * 64 + c];
        #pragma unroll
        for (int o = 0; o < 10; ++o) logit[o] += gv * Wfc[c * 10 + o];
    }
    float mx = logit[0];
    #pragma unroll
    for (int o = 1; o < 10; ++o) mx = fmaxf(mx, logit[o]);
    float se = 0.f;
    #pragma unroll
    for (int o = 0; o < 10; ++o) se += expf(logit[o] - mx);
    float lse = mx + logf(se);
    #pragma unroll
    for (int o = 0; o < 10; ++o) out[gi * 10 + o] = logit[o] - lse;
}

extern "C" void kernel_launch(void* const* d_in, const int* in_sizes, int n_in,
                              void* d_out, int out_size, void* d_ws, size_t ws_size,
                              hipStream_t stream) {
    const float* x        = (const float*)d_in[0];
    const float* W1       = (const float*)d_in[1];
    const float* att_src1 = (const float*)d_in[2];
    const float* att_dst1 = (const float*)d_in[3];
    const float* b1       = (const float*)d_in[4];
    const float* W2       = (const float*)d_in[5];
    const float* att_src2 = (const float*)d_in[6];
    const float* att_dst2 = (const float*)d_in[7];
    const float* b2       = (const float*)d_in[8];
    const float* Wfc      = (const float*)d_in[9];
    const float* bfc      = (const float*)d_in[10];
    const int*   eidx     = (const int*)d_in[11];
    const int*   batch    = (const int*)d_in[12];
    float* out = (float*)d_out;

    const int E  = in_sizes[11] / 2;
    const int* srcp = eidx;
    const int* dstp = eidx + E;

    // workspace layout (cursor and g contiguous -> single memset)
    char* w = (char*)d_ws;
    unsigned int* xwp = (unsigned int*)w;    w += (size_t)NNODES * 64 * 4;
    float* asrc = (float*)w;                 w += (size_t)NNODES * 2 * 4;
    float* adst = (float*)w;                 w += (size_t)NNODES * 2 * 4;
    unsigned short* h1 = (unsigned short*)w; w += (size_t)NNODES * 64 * 2;
    int* cursor  = (int*)w;                  w += (size_t)NNODES * 4;
    float* g    = (float*)w;                 w += (size_t)NGRAPHS * 64 * 4;
    int* esrc    = (int*)w;                  w += (size_t)NNODES * MAXDEG * 4;
    unsigned short* wt1 = (unsigned short*)w; w += (size_t)128 * 128 * 2;
    unsigned short* wt2 = (unsigned short*)w; w += (size_t)128 * 64 * 2;

    const int BLK = 256;
    int grid_e2   = ((E + 1) / 2 + BLK - 1) / BLK;
    int gemm_grid = (NNODES + 63) / 64;

    // ---- single memset for cursor + g ----
    hipMemsetAsync(cursor, 0, ((size_t)NNODES + NGRAPHS * 64) * 4, stream);

    // ---- CSR scatter (real edges only; cursor becomes deg) + W pre-conversion ----
    scatter_kernel<<<grid_e2, BLK, 0, stream>>>(srcp, dstp, cursor, esrc, E);
    prep_w_kernel<<<(128 * 192 + 255) / 256, 256, 0, stream>>>(W1, W2, wt1, wt2);

    // ---- layer 1 ----
    gemm_mfma_kernel<128, false><<<gemm_grid, BLK, 0, stream>>>(x, wt1, (unsigned short*)xwp,
                                                                att_src1, att_dst1, asrc, adst, NNODES);
    aggregate_kernel<false><<<NNODES, 64, 0, stream>>>(cursor, esrc,
                                                       (const float2*)asrc, (const float2*)adst,
                                                       xwp, b1, h1, nullptr, nullptr);

    // ---- layer 2 ----
    gemm_mfma_kernel<64, true><<<gemm_grid, BLK, 0, stream>>>(h1, wt2, (unsigned short*)xwp,
                                                              att_src2, att_dst2, asrc, adst, NNODES);
    aggregate_kernel<true><<<NNODES, 64, 0, stream>>>(cursor, esrc,
                                                      (const float2*)asrc, (const float2*)adst,
                                                      xwp, b2, nullptr, batch, g);

    // ---- final FC + log_softmax ----
    final_fc_kernel<<<1, 128, 0, stream>>>(g, Wfc, bfc, out);
}